// Round 1
// baseline (293.334 us; speedup 1.0000x reference)
//
#include <hip/hip_runtime.h>

#define TT 512
#define BB 64
#define DD 768

// ---------------------------------------------------------------------------
// Kernel 1: fused skinny GEMM  out1 = x@W1+b1 (L=2), out2 = x@W2+b2 (L=9)
// Block = 256 (4 waves). Each block owns 64 rows; wave w covers d in
// [w*192, w*192+192). Weights transposed in LDS, read at wave-uniform
// addresses (broadcast, bank-conflict free). Partial sums combined in LDS.
// ---------------------------------------------------------------------------
__global__ __launch_bounds__(256) void gemm_kernel(
    const float* __restrict__ x,
    const float* __restrict__ W1, const float* __restrict__ b1,
    const float* __restrict__ W2, const float* __restrict__ b2,
    float* __restrict__ o1, float* __restrict__ o2)
{
    __shared__ float wT[11][DD];          // wT[c][d]
    __shared__ float partial[4][64][13];  // [wave][row][col], pad 13 vs bank conflicts
    const int tid = threadIdx.x;

    for (int i = tid; i < DD * 2; i += 256) { wT[i & 1][i >> 1] = W1[i]; }
    for (int i = tid; i < DD * 9; i += 256) { int d = i / 9; wT[2 + (i - d * 9)][d] = W2[i]; }
    __syncthreads();

    const int wave = tid >> 6;
    const int lane = tid & 63;
    const int row  = blockIdx.x * 64 + lane;
    const int d0   = wave * 192;

    float acc[11];
#pragma unroll
    for (int c = 0; c < 11; ++c) acc[c] = 0.f;

    const float4* xrow = reinterpret_cast<const float4*>(x + (size_t)row * DD + d0);
    for (int ch = 0; ch < 48; ++ch) {
        float4 xv = xrow[ch];
        const int d = d0 + ch * 4;
#pragma unroll
        for (int c = 0; c < 11; ++c) {
            float4 wv = *reinterpret_cast<const float4*>(&wT[c][d]);
            acc[c] += xv.x * wv.x + xv.y * wv.y + xv.z * wv.z + xv.w * wv.w;
        }
    }
#pragma unroll
    for (int c = 0; c < 11; ++c) partial[wave][lane][c] = acc[c];
    __syncthreads();

    for (int o = tid; o < 64 * 11; o += 256) {
        int r = o / 11, c = o - r * 11;
        float s = partial[0][r][c] + partial[1][r][c] + partial[2][r][c] + partial[3][r][c];
        int grow = blockIdx.x * 64 + r;
        if (c < 2) o1[grow * 2 + c] = s + b1[c];
        else       o2[grow * 9 + (c - 2)] = s + b2[c - 2];
    }
}

// ---------------------------------------------------------------------------
// Kernel 2: per-sequence CRF work. One block per sequence (64 blocks, 256 thr).
//   wave 0: log-likelihood scan CRF1 (L=2), wave 1: ll scan CRF2 (L=9)
//   wave 2: viterbi CRF1,                 wave 3: viterbi CRF2
// Logits for the whole sequence staged in LDS. Scalar per-seq results to ws.
// ---------------------------------------------------------------------------
__global__ __launch_bounds__(256) void crf_kernel(
    const float* __restrict__ o1, const float* __restrict__ o2,
    const int* __restrict__ label, const int* __restrict__ seqlen,
    const float* __restrict__ trans1, const float* __restrict__ trans2,
    float* __restrict__ dout,
    float* __restrict__ ll1o, float* __restrict__ ll2o,
    float* __restrict__ c1o, float* __restrict__ c2o, float* __restrict__ cco)
{
    __shared__ float s_l1[TT][2];
    __shared__ float s_l2[TT][9];
    __shared__ float s_tr1[4];
    __shared__ float s_tr2[81];
    __shared__ int   s_lab[TT];
    __shared__ unsigned char s_bp1[TT][2];
    __shared__ unsigned char s_bp2[TT][9];
    __shared__ unsigned char s_v1[TT];
    __shared__ unsigned char s_v2[TT];
    __shared__ float s_sum[4];   // u1, b1s, u2, b2s
    __shared__ int   s_red[3][4];

    const int tid = threadIdx.x;
    const int b   = blockIdx.x;
    const int sl  = seqlen[b];

    for (int i = tid; i < TT * 2; i += 256) ((float*)s_l1)[i] = o1[b * TT * 2 + i];
    for (int i = tid; i < TT * 9; i += 256) ((float*)s_l2)[i] = o2[b * TT * 9 + i];
    for (int i = tid; i < TT;     i += 256) s_lab[i] = label[b * TT + i];
    if (tid < 4)  { s_tr1[tid] = trans1[tid]; s_sum[tid] = 0.f; }
    if (tid < 81) s_tr2[tid] = trans2[tid];
    __syncthreads();

    // ---- unary + binary scores (data-parallel, block reduction) ----
    {
        float a0 = 0.f, a1 = 0.f, a2 = 0.f, a3 = 0.f;
        for (int t = tid; t < sl; t += 256) {
            int lb = s_lab[t]; int lb1 = lb > 0 ? 1 : 0;
            a0 += s_l1[t][lb1];
            a2 += s_l2[t][lb];
            if (t >= 1) {
                int lp = s_lab[t - 1]; int lp1 = lp > 0 ? 1 : 0;
                a1 += s_tr1[lp1 * 2 + lb1];
                a3 += s_tr2[lp * 9 + lb];
            }
        }
        for (int off = 32; off; off >>= 1) {
            a0 += __shfl_down(a0, off); a1 += __shfl_down(a1, off);
            a2 += __shfl_down(a2, off); a3 += __shfl_down(a3, off);
        }
        if ((tid & 63) == 0) {
            atomicAdd(&s_sum[0], a0); atomicAdd(&s_sum[1], a1);
            atomicAdd(&s_sum[2], a2); atomicAdd(&s_sum[3], a3);
        }
    }
    __syncthreads();

    const int wave = tid >> 6;
    const int lane = tid & 63;

    if (wave == 0) {
        // ---- log-likelihood scan, CRF1 (L=2), scalar on lane 0 ----
        if (lane == 0) {
            float t00 = s_tr1[0], t01 = s_tr1[1], t10 = s_tr1[2], t11 = s_tr1[3];
            float a0v = s_l1[0][0], a1v = s_l1[0][1];
            for (int t = 1; t < sl; ++t) {
                float x0 = a0v + t00, y0 = a1v + t10;
                float m0 = fmaxf(x0, y0);
                float n0 = m0 + __logf(__expf(x0 - m0) + __expf(y0 - m0)) + s_l1[t][0];
                float x1 = a0v + t01, y1 = a1v + t11;
                float m1 = fmaxf(x1, y1);
                float n1 = m1 + __logf(__expf(x1 - m1) + __expf(y1 - m1)) + s_l1[t][1];
                a0v = n0; a1v = n1;
            }
            float m  = fmaxf(a0v, a1v);
            float ln = m + __logf(__expf(a0v - m) + __expf(a1v - m));
            ll1o[b] = s_sum[0] + s_sum[1] - ln;
        }
    } else if (wave == 1) {
        // ---- log-likelihood scan, CRF2 (L=9): lane j computes entry j ----
        const int j = lane < 9 ? lane : 0;
        float alpha[9], tc[9];
#pragma unroll
        for (int i = 0; i < 9; ++i) alpha[i] = s_l2[0][i];
#pragma unroll
        for (int i = 0; i < 9; ++i) tc[i] = s_tr2[i * 9 + j];
        for (int t = 1; t < sl; ++t) {
            float v[9];
#pragma unroll
            for (int i = 0; i < 9; ++i) v[i] = alpha[i] + tc[i];
            float m01 = fmaxf(v[0], v[1]), m23 = fmaxf(v[2], v[3]);
            float m45 = fmaxf(v[4], v[5]), m67 = fmaxf(v[6], v[7]);
            float m = fmaxf(fmaxf(fmaxf(m01, m23), fmaxf(m45, m67)), v[8]);
            float s = __expf(v[0] - m);
#pragma unroll
            for (int i = 1; i < 9; ++i) s += __expf(v[i] - m);
            float nj = m + __logf(s) + s_l2[t][j];
#pragma unroll
            for (int i = 0; i < 9; ++i) alpha[i] = __shfl(nj, i);
        }
        if (lane == 0) {
            float m = alpha[0];
#pragma unroll
            for (int i = 1; i < 9; ++i) m = fmaxf(m, alpha[i]);
            float s = __expf(alpha[0] - m);
#pragma unroll
            for (int i = 1; i < 9; ++i) s += __expf(alpha[i] - m);
            float ln = m + __logf(s);
            ll2o[b] = s_sum[2] + s_sum[3] - ln;
        }
    } else if (wave == 2) {
        // ---- viterbi CRF1 (L=2), scalar on lane 0 ----
        if (lane == 0) {
            float t00 = s_tr1[0], t01 = s_tr1[1], t10 = s_tr1[2], t11 = s_tr1[3];
            float a0v = s_l1[0][0], a1v = s_l1[0][1];
            for (int t = 1; t < sl; ++t) {
                float x0 = a0v + t00, y0 = a1v + t10;
                s_bp1[t][0] = (unsigned char)(y0 > x0 ? 1 : 0);   // first-max tie -> 0
                float n0 = fmaxf(x0, y0) + s_l1[t][0];
                float x1 = a0v + t01, y1 = a1v + t11;
                s_bp1[t][1] = (unsigned char)(y1 > x1 ? 1 : 0);
                float n1 = fmaxf(x1, y1) + s_l1[t][1];
                a0v = n0; a1v = n1;
            }
            int lastv = (a1v > a0v) ? 1 : 0;
            for (int t = sl - 1; t < TT; ++t) s_v1[t] = (unsigned char)lastv;
            __asm__ volatile("s_waitcnt lgkmcnt(0)" ::: "memory");
            int tag = lastv;
            for (int t = sl - 1; t >= 1; --t) { tag = s_bp1[t][tag]; s_v1[t - 1] = (unsigned char)tag; }
        }
    } else {
        // ---- viterbi CRF2 (L=9) ----
        const int j = lane < 9 ? lane : 0;
        float alpha[9], tc[9];
#pragma unroll
        for (int i = 0; i < 9; ++i) alpha[i] = s_l2[0][i];
#pragma unroll
        for (int i = 0; i < 9; ++i) tc[i] = s_tr2[i * 9 + j];
        for (int t = 1; t < sl; ++t) {
            float best = alpha[0] + tc[0]; int bi = 0;
#pragma unroll
            for (int i = 1; i < 9; ++i) {
                float v = alpha[i] + tc[i];
                if (v > best) { best = v; bi = i; }   // strict > keeps first max
            }
            float nj = best + s_l2[t][j];
            if (lane < 9) s_bp2[t][j] = (unsigned char)bi;
#pragma unroll
            for (int i = 0; i < 9; ++i) alpha[i] = __shfl(nj, i);
        }
        if (lane == 0) {
            int lastv = 0; float bv = alpha[0];
#pragma unroll
            for (int i = 1; i < 9; ++i) { if (alpha[i] > bv) { bv = alpha[i]; lastv = i; } }
            for (int t = sl - 1; t < TT; ++t) s_v2[t] = (unsigned char)lastv;
            __asm__ volatile("s_waitcnt lgkmcnt(0)" ::: "memory");
            int tag = lastv;
            for (int t = sl - 1; t >= 1; --t) { tag = s_bp2[t][tag]; s_v2[t - 1] = (unsigned char)tag; }
        }
    }
    __syncthreads();

    // ---- combined viterbi output + accuracy counts ----
    {
        int c1 = 0, c2 = 0, cc = 0;
        for (int t = tid; t < TT; t += 256) {
            int p1 = s_v1[t], p2 = s_v2[t];
            int comb = (p1 == 0) ? 0 : p2;
            dout[b * TT + t] = (float)comb;
            if (t < sl) {
                int lb = s_lab[t]; int lb1 = lb > 0 ? 1 : 0;
                c1 += (p1 == lb1) ? 1 : 0;
                c2 += (p2 == lb)  ? 1 : 0;
                cc += (comb == lb) ? 1 : 0;
            }
        }
        for (int off = 32; off; off >>= 1) {
            c1 += __shfl_down(c1, off); c2 += __shfl_down(c2, off); cc += __shfl_down(cc, off);
        }
        if (lane == 0) { s_red[0][wave] = c1; s_red[1][wave] = c2; s_red[2][wave] = cc; }
    }
    __syncthreads();
    if (tid == 0) {
        c1o[b] = (float)(s_red[0][0] + s_red[0][1] + s_red[0][2] + s_red[0][3]);
        c2o[b] = (float)(s_red[1][0] + s_red[1][1] + s_red[1][2] + s_red[1][3]);
        cco[b] = (float)(s_red[2][0] + s_red[2][1] + s_red[2][2] + s_red[2][3]);
    }
}

// ---------------------------------------------------------------------------
// Kernel 3: final scalar reduction (1 block, 64 threads = one wave)
// ---------------------------------------------------------------------------
__global__ __launch_bounds__(64) void finalize_kernel(
    const float* __restrict__ ll1, const float* __restrict__ ll2,
    const float* __restrict__ c1, const float* __restrict__ c2,
    const float* __restrict__ cc, const int* __restrict__ seqlen,
    float* __restrict__ out)
{
    const int t = threadIdx.x;
    float v1 = ll1[t], v2 = ll2[t];
    float a1 = c1[t], a2 = c2[t], ac = cc[t];
    float slf = (float)seqlen[t];
    for (int off = 32; off; off >>= 1) {
        v1 += __shfl_down(v1, off); v2 += __shfl_down(v2, off);
        a1 += __shfl_down(a1, off); a2 += __shfl_down(a2, off);
        ac += __shfl_down(ac, off); slf += __shfl_down(slf, off);
    }
    if (t == 0) {
        float loss1 = -v1 / 64.f;
        float loss2 = -v2 / 64.f;
        out[BB * TT + 0] = (loss1 + 8.f * loss2) / 9.f;
        out[BB * TT + 1] = a1 / slf;
        out[BB * TT + 2] = a2 / slf;
        out[BB * TT + 3] = ac / slf;
    }
}

extern "C" void kernel_launch(void* const* d_in, const int* in_sizes, int n_in,
                              void* d_out, int out_size, void* d_ws, size_t ws_size,
                              hipStream_t stream) {
    (void)in_sizes; (void)n_in; (void)out_size; (void)ws_size;
    const float* x      = (const float*)d_in[0];
    const int*   label  = (const int*)d_in[1];
    const int*   seqlen = (const int*)d_in[2];
    const float* W1     = (const float*)d_in[3];
    const float* b1     = (const float*)d_in[4];
    const float* W2     = (const float*)d_in[5];
    const float* b2     = (const float*)d_in[6];
    const float* trans1 = (const float*)d_in[7];
    const float* trans2 = (const float*)d_in[8];
    float* out = (float*)d_out;
    float* ws  = (float*)d_ws;

    float* o1  = ws;                 // 32768*2 floats
    float* o2  = o1 + BB * TT * 2;   // 32768*9 floats
    float* ll1 = o2 + BB * TT * 9;   // 64
    float* ll2 = ll1 + BB;
    float* c1  = ll2 + BB;
    float* c2  = c1 + BB;
    float* cc  = c2 + BB;

    gemm_kernel<<<512, 256, 0, stream>>>(x, W1, b1, W2, b2, o1, o2);
    crf_kernel<<<64, 256, 0, stream>>>(o1, o2, label, seqlen, trans1, trans2,
                                       out, ll1, ll2, c1, c2, cc);
    finalize_kernel<<<1, 64, 0, stream>>>(ll1, ll2, c1, c2, cc, seqlen, out);
}